// Round 10
// baseline (591.491 us; speedup 1.0000x reference)
//
#include <hip/hip_runtime.h>
#include <hip/hip_fp16.h>
#include <math.h>

#define SEQ   2048
#define HID   1024
#define NH    16
#define HD    64
#define NKH   204          // heavy hitters = int(2048*0.1)
#define LCOMP 512          // compressed length = 2048/4
#define NCAT  716          // 204 + 512
#define NCATP 768          // padded to multiple of 64 (52 pad keys)
#define SCALE 0.125f       // 1/sqrt(64)

typedef __attribute__((ext_vector_type(8))) short short8;   // 8 bf16 (4 VGPRs)
typedef __attribute__((ext_vector_type(4))) float f32x4;    // MFMA accumulator

// ---- bf16 split helpers (RNE) -------------------------------------------
__device__ __forceinline__ short f2bf(float f) {
    unsigned u = __builtin_bit_cast(unsigned, f);
    u += 0x7FFFu + ((u >> 16) & 1u);
    return (short)(u >> 16);
}
__device__ __forceinline__ float bf2f(short h) {
    unsigned u = ((unsigned)(unsigned short)h) << 16;
    return __builtin_bit_cast(float, u);
}

// ---------------------------------------------------------------------------
// One-pass splitters: f32 -> bf16 hi/lo.
// ---------------------------------------------------------------------------
__global__ __launch_bounds__(256) void splitx_k(const float* __restrict__ X,
                                                unsigned short* __restrict__ hi,
                                                unsigned short* __restrict__ lo) {
    size_t g = ((size_t)blockIdx.x * 256 + threadIdx.x) * 4;
    float4 v4 = *(const float4*)(X + g);
    ushort4 h4, l4;
    short hb;
    hb = f2bf(v4.x); h4.x = hb; l4.x = (unsigned short)f2bf(v4.x - bf2f(hb));
    hb = f2bf(v4.y); h4.y = hb; l4.y = (unsigned short)f2bf(v4.y - bf2f(hb));
    hb = f2bf(v4.z); h4.z = hb; l4.z = (unsigned short)f2bf(v4.z - bf2f(hb));
    hb = f2bf(v4.w); h4.w = hb; l4.w = (unsigned short)f2bf(v4.w - bf2f(hb));
    *(ushort4*)(hi + g) = h4;
    *(ushort4*)(lo + g) = l4;
}

// All 4 weight splits in one launch; blockIdx.z picks src/dst (wave-uniform).
__global__ __launch_bounds__(256) void splitw4_k(const float* __restrict__ W0,
                                                 const float* __restrict__ W1,
                                                 const float* __restrict__ W2,
                                                 const float* __restrict__ W3,
                                                 unsigned short* __restrict__ h012,
                                                 unsigned short* __restrict__ l012,
                                                 unsigned short* __restrict__ h3,
                                                 unsigned short* __restrict__ l3) {
    __shared__ float tile[64][65];
    int z = blockIdx.z;
    const float* W = (z == 0) ? W0 : (z == 1) ? W1 : (z == 2) ? W2 : W3;
    unsigned short* hi = (z == 3) ? h3 : h012 + (size_t)z * HID * HID;
    unsigned short* lo = (z == 3) ? l3 : l012 + (size_t)z * HID * HID;
    int n0 = blockIdx.x * 64, k0 = blockIdx.y * 64;
    int t = threadIdx.x;
    int r = t >> 4, c4 = (t & 15) * 4;
    #pragma unroll
    for (int i = 0; i < 4; ++i) {
        float4 v4 = *(const float4*)(W + (size_t)(k0 + i*16 + r) * HID + n0 + c4);
        tile[i*16 + r][c4+0] = v4.x; tile[i*16 + r][c4+1] = v4.y;
        tile[i*16 + r][c4+2] = v4.z; tile[i*16 + r][c4+3] = v4.w;
    }
    __syncthreads();
    #pragma unroll
    for (int i = 0; i < 4; ++i) {
        int n = i*16 + r;
        float v0 = tile[c4+0][n], v1 = tile[c4+1][n];
        float v2 = tile[c4+2][n], v3 = tile[c4+3][n];
        ushort4 h4, l4;
        short hb;
        hb = f2bf(v0); h4.x = hb; l4.x = (unsigned short)f2bf(v0 - bf2f(hb));
        hb = f2bf(v1); h4.y = hb; l4.y = (unsigned short)f2bf(v1 - bf2f(hb));
        hb = f2bf(v2); h4.z = hb; l4.z = (unsigned short)f2bf(v2 - bf2f(hb));
        hb = f2bf(v3); h4.w = hb; l4.w = (unsigned short)f2bf(v3 - bf2f(hb));
        size_t o = (size_t)(n0 + n) * HID + k0 + c4;
        *(ushort4*)(hi + o) = h4;
        *(ushort4*)(lo + o) = l4;
    }
}

// ---------------------------------------------------------------------------
// LDS-staged bf16x3 MFMA GEMM.  Block = BM x BN, BK=32, 4 waves,
// wave = (BM/2)m x (BN/2)n.  MODE 1 = fused QKV epilogue, MODE 0 = f32 C.
// ---------------------------------------------------------------------------
template<int BM, int BN, int MODE>
__global__ __launch_bounds__(256) void gemm_lds(const unsigned short* __restrict__ Ahi,
                                                const unsigned short* __restrict__ Alo,
                                                const unsigned short* __restrict__ Bthi,
                                                const unsigned short* __restrict__ Btlo,
                                                unsigned short* __restrict__ qhi,
                                                unsigned short* __restrict__ qlo,
                                                float* __restrict__ kf,
                                                unsigned short* __restrict__ khi,
                                                unsigned short* __restrict__ klo,
                                                float* __restrict__ vf,
                                                float* __restrict__ Cf) {
    constexpr int WM = BM / 2, WN = BN / 2;
    constexpr int MT = WM / 16, NT = WN / 16;
    __shared__ __align__(16) unsigned short Ah_s[BM * 32];
    __shared__ __align__(16) unsigned short Al_s[BM * 32];
    __shared__ __align__(16) unsigned short Bh_s[BN * 32];
    __shared__ __align__(16) unsigned short Bl_s[BN * 32];
    int t = threadIdx.x, lane = t & 63, w = t >> 6;
    int quad = lane >> 4, c16 = lane & 15;
    int m0 = blockIdx.x * BM, n0 = blockIdx.y * BN;
    int moff = (w & 1) * WM, noff = (w >> 1) * WN;
    int sr = t >> 2, skq = (t & 3) * 8;          // staging: row, k-offset

    f32x4 acc[MT][NT];
    #pragma unroll
    for (int mt = 0; mt < MT; ++mt)
        #pragma unroll
        for (int nt = 0; nt < NT; ++nt)
            acc[mt][nt] = (f32x4){0.f, 0.f, 0.f, 0.f};

    for (int kt = 0; kt < HID; kt += 32) {
        __syncthreads();
        #pragma unroll
        for (int p = 0; p < BM / 64; ++p) {
            int row = p * 64 + sr;
            *(short8*)&Ah_s[row * 32 + skq] =
                *(const short8*)(Ahi + (size_t)(m0 + row) * HID + kt + skq);
            *(short8*)&Al_s[row * 32 + skq] =
                *(const short8*)(Alo + (size_t)(m0 + row) * HID + kt + skq);
        }
        #pragma unroll
        for (int p = 0; p < BN / 64; ++p) {
            int row = p * 64 + sr;
            *(short8*)&Bh_s[row * 32 + skq] =
                *(const short8*)(Bthi + (size_t)(n0 + row) * HID + kt + skq);
            *(short8*)&Bl_s[row * 32 + skq] =
                *(const short8*)(Btlo + (size_t)(n0 + row) * HID + kt + skq);
        }
        __syncthreads();
        short8 Bh[NT], Bl[NT];
        #pragma unroll
        for (int nt = 0; nt < NT; ++nt) {
            int row = noff + nt * 16 + c16;
            Bh[nt] = *(const short8*)&Bh_s[row * 32 + quad * 8];
            Bl[nt] = *(const short8*)&Bl_s[row * 32 + quad * 8];
        }
        #pragma unroll
        for (int mt = 0; mt < MT; ++mt) {
            int row = moff + mt * 16 + c16;
            short8 Ah = *(const short8*)&Ah_s[row * 32 + quad * 8];
            short8 Al = *(const short8*)&Al_s[row * 32 + quad * 8];
            #pragma unroll
            for (int nt = 0; nt < NT; ++nt) {
                acc[mt][nt] = __builtin_amdgcn_mfma_f32_16x16x32_bf16(Ah, Bh[nt], acc[mt][nt], 0, 0, 0);
                acc[mt][nt] = __builtin_amdgcn_mfma_f32_16x16x32_bf16(Al, Bh[nt], acc[mt][nt], 0, 0, 0);
                acc[mt][nt] = __builtin_amdgcn_mfma_f32_16x16x32_bf16(Ah, Bl[nt], acc[mt][nt], 0, 0, 0);
            }
        }
    }

    #pragma unroll
    for (int mt = 0; mt < MT; ++mt)
    #pragma unroll
    for (int nt = 0; nt < NT; ++nt)
    #pragma unroll
    for (int i = 0; i < 4; ++i) {
        int m  = m0 + moff + mt * 16 + quad * 4 + i;
        int ng = n0 + noff + nt * 16 + c16;
        float val = acc[mt][nt][i];
        if (MODE == 1) {
            int seg = ng >> 10;            // 0=q, 1=k, 2=v
            int nl  = ng & 1023;
            if (seg == 0) {
                size_t o = ((size_t)(nl >> 6) * SEQ + m) * HD + (nl & 63);
                short hb = f2bf(val);
                qhi[o] = (unsigned short)hb;
                qlo[o] = (unsigned short)f2bf(val - bf2f(hb));
            } else if (seg == 1) {
                kf[(size_t)m * HID + nl] = val;
                size_t o = ((size_t)(nl >> 6) * SEQ + m) * HD + (nl & 63);
                short hb = f2bf(val);
                khi[o] = (unsigned short)hb;
                klo[o] = (unsigned short)f2bf(val - bf2f(hb));
            } else {
                vf[(size_t)m * HID + nl] = val;
            }
        } else {
            Cf[(size_t)m * HID + ng] = val;
        }
    }
}

// ---------------------------------------------------------------------------
// Score stats v5: 16-row blocks (grid 2048 -> 8 blocks/CU of latency-hiding
// TLP), two-pass recompute, no score storage.  Wave w owns keys [w*512,+512).
// mx tracked on tt=exp(s) (monotone => identical result bits).
// ---------------------------------------------------------------------------
__global__ __launch_bounds__(256) void score_mfma(const unsigned short* __restrict__ qhi,
                                                  const unsigned short* __restrict__ qlo,
                                                  const unsigned short* __restrict__ khi,
                                                  const unsigned short* __restrict__ klo,
                                                  float* __restrict__ ent,
                                                  float* __restrict__ mxa,
                                                  __half* __restrict__ part) {
    __shared__ float redm[4][16], redl[4][16], rede[4][16];
    int h  = blockIdx.x;
    int qb = blockIdx.y;
    int m0 = qb * 16;
    int t  = threadIdx.x;
    int lane = t & 63, w = t >> 6;
    int quad = lane >> 4, c16 = lane & 15;

    const unsigned short* qph = qhi + ((size_t)h * SEQ + m0 + c16) * HD;
    const unsigned short* qpl = qlo + ((size_t)h * SEQ + m0 + c16) * HD;
    short8 Ah0 = *(const short8*)(qph + quad*8);
    short8 Ah1 = *(const short8*)(qph + 32 + quad*8);
    short8 Al0 = *(const short8*)(qpl + quad*8);
    short8 Al1 = *(const short8*)(qpl + 32 + quad*8);

    // ---- pass 1: l = sum exp(s), ee = sum exp(s)*s, mx = max exp(s) ----
    float l[4] = {}, ee[4] = {}, mx[4] = {};
    #pragma unroll
    for (int nt = 0; nt < 32; ++nt) {
        int key = (w * 32 + nt) * 16 + c16;
        const unsigned short* kbh = khi + ((size_t)h * SEQ + key) * HD;
        const unsigned short* kbl = klo + ((size_t)h * SEQ + key) * HD;
        short8 Bh0 = *(const short8*)(kbh + quad*8);
        short8 Bh1 = *(const short8*)(kbh + 32 + quad*8);
        short8 Bl0 = *(const short8*)(kbl + quad*8);
        short8 Bl1 = *(const short8*)(kbl + 32 + quad*8);
        f32x4 acc = {0.f, 0.f, 0.f, 0.f};
        acc = __builtin_amdgcn_mfma_f32_16x16x32_bf16(Ah0, Bh0, acc, 0, 0, 0);
        acc = __builtin_amdgcn_mfma_f32_16x16x32_bf16(Al0, Bh0, acc, 0, 0, 0);
        acc = __builtin_amdgcn_mfma_f32_16x16x32_bf16(Ah0, Bl0, acc, 0, 0, 0);
        acc = __builtin_amdgcn_mfma_f32_16x16x32_bf16(Ah1, Bh1, acc, 0, 0, 0);
        acc = __builtin_amdgcn_mfma_f32_16x16x32_bf16(Al1, Bh1, acc, 0, 0, 0);
        acc = __builtin_amdgcn_mfma_f32_16x16x32_bf16(Ah1, Bl1, acc, 0, 0, 0);
        #pragma unroll
        for (int i = 0; i < 4; ++i) {
            float s = acc[i] * SCALE;
            float tt = __expf(s);          // safe: |s| << 88
            l[i] += tt;
            ee[i] += tt * s;
            mx[i] = fmaxf(mx[i], tt);
        }
    }
    #pragma unroll
    for (int i = 0; i < 4; ++i) {
        #pragma unroll
        for (int off = 1; off <= 8; off <<= 1) {
            l[i]  += __shfl_xor(l[i], off);
            ee[i] += __shfl_xor(ee[i], off);
            mx[i]  = fmaxf(mx[i], __shfl_xor(mx[i], off));
        }
    }
    if (c16 == 0) {
        #pragma unroll
        for (int i = 0; i < 4; ++i) {
            int row = quad*4 + i;
            redl[w][row] = l[i];
            rede[w][row] = ee[i];
            redm[w][row] = mx[i];
        }
    }
    __syncthreads();
    float inv[4];
    #pragma unroll
    for (int i = 0; i < 4; ++i) {
        int row = quad*4 + i;
        float lf = redl[0][row] + redl[1][row] + redl[2][row] + redl[3][row];
        inv[i] = 1.f / lf;
        if (w == 0 && c16 == 0) {
            float eef = rede[0][row] + rede[1][row] + rede[2][row] + rede[3][row];
            float mf  = fmaxf(fmaxf(redm[0][row], redm[1][row]),
                              fmaxf(redm[2][row], redm[3][row]));
            mxa[h*SEQ + m0 + row] = mf * inv[i];
            ent[h*SEQ + m0 + row] = __logf(lf) - eef * inv[i];
        }
    }

    // ---- pass 2: recompute QK, emit influence column sums (f16) ----
    __half* pslab = part + (size_t)(h * (SEQ/16) + qb) * SEQ;
    #pragma unroll
    for (int nt = 0; nt < 32; ++nt) {
        int key = (w * 32 + nt) * 16 + c16;
        const unsigned short* kbh = khi + ((size_t)h * SEQ + key) * HD;
        const unsigned short* kbl = klo + ((size_t)h * SEQ + key) * HD;
        short8 Bh0 = *(const short8*)(kbh + quad*8);
        short8 Bh1 = *(const short8*)(kbh + 32 + quad*8);
        short8 Bl0 = *(const short8*)(kbl + quad*8);
        short8 Bl1 = *(const short8*)(kbl + 32 + quad*8);
        f32x4 acc = {0.f, 0.f, 0.f, 0.f};
        acc = __builtin_amdgcn_mfma_f32_16x16x32_bf16(Ah0, Bh0, acc, 0, 0, 0);
        acc = __builtin_amdgcn_mfma_f32_16x16x32_bf16(Al0, Bh0, acc, 0, 0, 0);
        acc = __builtin_amdgcn_mfma_f32_16x16x32_bf16(Ah0, Bl0, acc, 0, 0, 0);
        acc = __builtin_amdgcn_mfma_f32_16x16x32_bf16(Ah1, Bh1, acc, 0, 0, 0);
        acc = __builtin_amdgcn_mfma_f32_16x16x32_bf16(Al1, Bh1, acc, 0, 0, 0);
        acc = __builtin_amdgcn_mfma_f32_16x16x32_bf16(Ah1, Bl1, acc, 0, 0, 0);
        float cs = 0.f;
        #pragma unroll
        for (int i = 0; i < 4; ++i)
            cs += __expf(acc[i] * SCALE) * inv[i];
        cs += __shfl_xor(cs, 16);
        cs += __shfl_xor(cs, 32);           // sum over all 16 rows (4 quads)
        if (lane < 16) pslab[(w*32 + nt)*16 + lane] = __float2half(cs);
    }
}

// stage-1 influence reduction: red[g][s] = sum of 32 slabs (f16 -> f32)
__global__ __launch_bounds__(256) void reduce_infl(const __half* __restrict__ part,
                                                   float* __restrict__ red) {
    int s = blockIdx.x * 256 + threadIdx.x;
    int g = blockIdx.y;
    const __half* p = part + (size_t)g * 32 * SEQ + s;
    float a = 0.f;
    #pragma unroll 8
    for (int i = 0; i < 32; ++i) a += __half2float(p[(size_t)i * SEQ]);
    red[(size_t)g * SEQ + s] = a;
}

__global__ __launch_bounds__(256) void importance_k(const float* __restrict__ ent,
                                                    const float* __restrict__ mxa,
                                                    const float* __restrict__ red,
                                                    float* __restrict__ imp) {
    int s = blockIdx.x * 256 + threadIdx.x;
    float es = 0.f, ms = 0.f;
    #pragma unroll
    for (int h = 0; h < NH; ++h) { es += ent[h*SEQ + s]; ms += mxa[h*SEQ + s]; }
    float inf = 0.f;
    #pragma unroll 8
    for (int g = 0; g < 64; ++g) inf += red[(size_t)g * SEQ + s];
    imp[s] = (-0.4f*es + 0.3f*ms + 0.3f*inf) * (1.f/16.f);
}

// Deterministic top-k by rank counting (matches lax.top_k set semantics).
__global__ __launch_bounds__(256) void topk_k(const float* __restrict__ imp,
                                              int* __restrict__ hh) {
    __shared__ float si[SEQ];
    int t = threadIdx.x, s = blockIdx.x * 256 + t;
    for (int i = t; i < SEQ; i += 256) si[i] = imp[i];
    __syncthreads();
    float v = si[s];
    int rank = 0;
    #pragma unroll 1
    for (int i = 0; i < SEQ; ++i) {
        float u = si[i];
        rank += (u > v) || (u == v && i < s);
    }
    if (rank < NKH) hh[rank] = s;
}

// per-(h,s) L2 norms for BOTH k and v (blockIdx.y selects tensor)
__global__ __launch_bounds__(256) void norms2_k(const float* __restrict__ kf,
                                                const float* __restrict__ vf,
                                                float* __restrict__ wk,
                                                float* __restrict__ wv) {
    int sel = blockIdx.y;
    const float* x = sel ? vf : kf;
    float* n = sel ? wv : wk;
    int t = threadIdx.x;
    int wid = blockIdx.x * 4 + (t >> 6);
    int lane = t & 63;
    int h = wid >> 11, s = wid & 2047;
    float v = x[(size_t)s * HID + h * HD + lane];
    float ss = v * v;
    #pragma unroll
    for (int off = 32; off; off >>= 1) ss += __shfl_xor(ss, off);
    if (lane == 0) n[h*SEQ + s] = sqrtf(ss);
}

// in-place softmax over SEQ per head for BOTH wk and wv
__global__ __launch_bounds__(256) void softw2_k(float* __restrict__ wk,
                                                float* __restrict__ wv) {
    __shared__ float red[8];
    int h = blockIdx.x, t = threadIdx.x, lane = t & 63, w = t >> 6;
    float* nh = (blockIdx.y ? wv : wk) + (size_t)h * SEQ;
    float m = -1e30f;
    for (int i = t; i < SEQ; i += 256) m = fmaxf(m, nh[i]);
    #pragma unroll
    for (int off = 32; off; off >>= 1) m = fmaxf(m, __shfl_xor(m, off));
    if (lane == 0) red[w] = m;
    __syncthreads();
    m = fmaxf(fmaxf(red[0], red[1]), fmaxf(red[2], red[3]));
    float z = 0.f;
    for (int i = t; i < SEQ; i += 256) z += __expf(nh[i] - m);
    #pragma unroll
    for (int off = 32; off; off >>= 1) z += __shfl_xor(z, off);
    if (lane == 0) red[4 + w] = z;
    __syncthreads();
    z = red[4] + red[5] + red[6] + red[7];
    for (int i = t; i < SEQ; i += 256) nh[i] = __expf(nh[i] - m) / z;
}

// group-4 weighted pooling of K (direct) and V (transposed) in one launch
__global__ __launch_bounds__(256) void pool2_k(const float* __restrict__ kf,
                                               const float* __restrict__ vf,
                                               const float* __restrict__ wk,
                                               const float* __restrict__ wv,
                                               unsigned short* __restrict__ khi,
                                               unsigned short* __restrict__ klo,
                                               unsigned short* __restrict__ vthi,
                                               unsigned short* __restrict__ vtlo) {
    int sel = blockIdx.y;
    const float* src = sel ? vf : kf;
    const float* w   = sel ? wv : wk;
    int g = blockIdx.x * 256 + threadIdx.x;
    int d = g & 63, rest = g >> 6;
    int l = rest & 511, h = rest >> 9;
    const float* wp = w + (size_t)h * SEQ + l * 4;
    float w0 = wp[0], w1 = wp[1], w2 = wp[2], w3 = wp[3];
    float wsum = w0 + w1 + w2 + w3 + 1e-8f;
    size_t base = (size_t)(l*4) * HID + h * HD + d;
    float val = (src[base]*w0 + src[base+HID]*w1 + src[base+2*HID]*w2 + src[base+3*HID]*w3) / wsum;
    short hb = f2bf(val);
    if (sel) {
        size_t dst = ((size_t)h * HD + d) * NCATP + NKH + l;
        vthi[dst] = (unsigned short)hb;
        vtlo[dst] = (unsigned short)f2bf(val - bf2f(hb));
    } else {
        size_t dst = ((size_t)h * NCATP + NKH + l) * HD + d;
        khi[dst] = (unsigned short)hb;
        klo[dst] = (unsigned short)f2bf(val - bf2f(hb));
    }
}

// gather heavy-hitter k/v rows -> pre-split bf16 (K direct, V transposed)
__global__ __launch_bounds__(256) void gather_k(const float* __restrict__ k,
                                                const float* __restrict__ v,
                                                const int* __restrict__ hh,
                                                unsigned short* __restrict__ khi,
                                                unsigned short* __restrict__ klo,
                                                unsigned short* __restrict__ vthi,
                                                unsigned short* __restrict__ vtlo) {
    int g = blockIdx.x * 256 + threadIdx.x;
    int d = g & 63, rest = g >> 6;
    int i = rest % NKH, h = rest / NKH;
    int s = hh[i];
    float kv = k[(size_t)s * HID + h * HD + d];
    float vv = v[(size_t)s * HID + h * HD + d];
    size_t kd = ((size_t)h * NCATP + i) * HD + d;
    size_t vd = ((size_t)h * HD + d) * NCATP + i;
    short hb = f2bf(kv);
    khi[kd] = (unsigned short)hb;
    klo[kd] = (unsigned short)f2bf(kv - bf2f(hb));
    hb = f2bf(vv);
    vthi[vd] = (unsigned short)hb;
    vtlo[vd] = (unsigned short)f2bf(vv - bf2f(hb));
}

// zero the 52 pad keys per head in all four split arrays
__global__ __launch_bounds__(256) void padzero_k(unsigned short* __restrict__ khi,
                                                 unsigned short* __restrict__ klo,
                                                 unsigned short* __restrict__ vthi,
                                                 unsigned short* __restrict__ vtlo) {
    int g = blockIdx.x * 256 + threadIdx.x;
    if (g >= NH * (NCATP - NCAT) * HD) return;
    int d = g & 63, rest = g >> 6;
    int i = rest % (NCATP - NCAT), h = rest / (NCATP - NCAT);
    size_t kd = ((size_t)h * NCATP + NCAT + i) * HD + d;
    size_t vd = ((size_t)h * HD + d) * NCATP + NCAT + i;
    khi[kd] = 0; klo[kd] = 0;
    vthi[vd] = 0; vtlo[vd] = 0;
}

// ---------------------------------------------------------------------------
// Final attention via bf16x3 MFMA + __expf (unchanged).
// ---------------------------------------------------------------------------
__global__ __launch_bounds__(256) void attn_mfma(const unsigned short* __restrict__ qhi,
                                                 const unsigned short* __restrict__ qlo,
                                                 const unsigned short* __restrict__ kchi,
                                                 const unsigned short* __restrict__ kclo,
                                                 const unsigned short* __restrict__ vthi,
                                                 const unsigned short* __restrict__ vtlo,
                                                 unsigned short* __restrict__ aohi,
                                                 unsigned short* __restrict__ aolo) {
    __shared__ unsigned short phi[16][776];
    __shared__ unsigned short plo[16][776];
    __shared__ float redm[4][16], redl[4][16];
    int h  = blockIdx.x;
    int m0 = blockIdx.y * 16;
    int t  = threadIdx.x;
    int lane = t & 63, w = t >> 6;
    int quad = lane >> 4, c16 = lane & 15;

    const unsigned short* qph = qhi + ((size_t)h * SEQ + m0 + c16) * HD;
    const unsigned short* qpl = qlo + ((size_t)h * SEQ + m0 + c16) * HD;
    short8 Ah0 = *(const short8*)(qph + quad*8);
    short8 Ah1 = *(const short8*)(qph + 32 + quad*8);
    short8 Al0 = *(const short8*)(qpl + quad*8);
    short8 Al1 = *(const short8*)(qpl + 32 + quad*8);

    float sreg[12][4];
    #pragma unroll
    for (int nt = 0; nt < 12; ++nt) {
        int key = w*192 + nt*16 + c16;
        const unsigned short* kbh = kchi + ((size_t)h * NCATP + key) * HD;
        const unsigned short* kbl = kclo + ((size_t)h * NCATP + key) * HD;
        short8 Bh0 = *(const short8*)(kbh + quad*8);
        short8 Bh1 = *(const short8*)(kbh + 32 + quad*8);
        short8 Bl0 = *(const short8*)(kbl + quad*8);
        short8 Bl1 = *(const short8*)(kbl + 32 + quad*8);
        f32x4 acc = {0.f, 0.f, 0.f, 0.f};
        acc = __builtin_amdgcn_mfma_f32_16x16x32_bf16(Ah0, Bh0, acc, 0, 0, 0);
        acc = __builtin_amdgcn_mfma_f32_16x16x32_bf16(Al0, Bh0, acc, 0, 0, 0);
        acc = __builtin_amdgcn_mfma_f32_16x16x32_bf16(Ah0, Bl0, acc, 0, 0, 0);
        acc = __builtin_amdgcn_mfma_f32_16x16x32_bf16(Ah1, Bh1, acc, 0, 0, 0);
        acc = __builtin_amdgcn_mfma_f32_16x16x32_bf16(Al1, Bh1, acc, 0, 0, 0);
        acc = __builtin_amdgcn_mfma_f32_16x16x32_bf16(Ah1, Bl1, acc, 0, 0, 0);
        bool bad = key >= NCAT;
        #pragma unroll
        for (int i = 0; i < 4; ++i)
            sreg[nt][i] = bad ? -1e30f : acc[i] * SCALE;
    }

    float m[4], l[4];
    #pragma unroll
    for (int i = 0; i < 4; ++i) {
        float mm = -1e30f;
        #pragma unroll
        for (int nt = 0; nt < 12; ++nt) mm = fmaxf(mm, sreg[nt][i]);
        #pragma unroll
        for (int off = 1; off <= 8; off <<= 1) mm = fmaxf(mm, __shfl_xor(mm, off));
        m[i] = mm;
    }
    if (c16 == 0) {
        #pragma unroll
        for (int i = 0; i < 4; ++i) redm[w][quad*4 + i] = m[i];
    }
    __syncthreads();
    #pragma unroll
    for (int i = 0; i < 4; ++i) {
        int row = quad*4 + i;
        m[i] = fmaxf(fmaxf(redm[0][row], redm[1][row]),
                     fmaxf(redm[2][row], redm[3][row]));
    }
    #pragma unroll
    for (int i = 0; i < 4; ++i) {
        float ll = 0.f;
        #pragma unroll
        for (int nt = 0; nt < 12; ++nt) ll += __expf(sreg[nt][i] - m[i]);
        #pragma unroll
        for (int off = 1; off <= 8; off <<= 1) ll += __shfl_xor(ll, off);
        l[i] = ll;
    }
    if (c16 == 0) {
        #pragma unroll
        for (int i = 0; i < 4; ++i) redl[w][quad*4 + i] = l[i];
    }
    __syncthreads();
    float inv[4];
    #pragma unroll
    for (int i = 0; i < 4; ++i) {
        int row = quad*4 + i;
        inv[i] = 1.f / (redl[0][row] + redl[1][row] + redl[2][row] + redl[3][row]);
    }

    #pragma unroll
    for (int nt = 0; nt < 12; ++nt) {
        int key = w*192 + nt*16 + c16;
        #pragma unroll
        for (int i = 0; i < 4; ++i) {
            float p = __expf(sreg[nt][i] - m[i]) * inv[i];
            short ph = f2bf(p);
            phi[quad*4 + i][key] = (unsigned short)ph;
            plo[quad*4 + i][key] = (unsigned short)f2bf(p - bf2f(ph));
        }
    }
    __syncthreads();

    int dim = w*16 + c16;
    const unsigned short* vh = vthi + ((size_t)h * HD + dim) * NCATP;
    const unsigned short* vl = vtlo + ((size_t)h * HD + dim) * NCATP;
    f32x4 ohh = {0.f,0.f,0.f,0.f}, olh = {0.f,0.f,0.f,0.f}, ohl = {0.f,0.f,0.f,0.f};
    #pragma unroll 4
    for (int s = 0; s < 24; ++s) {
        int k0 = s*32 + quad*8;
        short8 Ph = *(const short8*)&phi[c16][k0];
        short8 Pl = *(const short8*)&plo[c16][k0];
        short8 Vh = *(const short8*)(vh + k0);
        short8 Vl = *(const short8*)(vl + k0);
        ohh = __builtin_amdgcn_mfma_f32_16x16x32_bf16(Ph, Vh, ohh, 0, 0, 0);
        olh = __builtin_amdgcn_mfma_f32_16x16x32_bf16(Pl, Vh, olh, 0, 0, 0);
        ohl = __builtin_amdgcn_mfma_f32_16x16x32_bf16(Ph, Vl, ohl, 0, 0, 0);
    }
    #pragma unroll
    for (int i = 0; i < 4; ++i) {
        float val = ohh[i] + olh[i] + ohl[i];
        size_t o = (size_t)(m0 + quad*4 + i) * HID + h * HD + dim;
        short hb = f2bf(val);
        aohi[o] = (unsigned short)hb;
        aolo[o] = (unsigned short)f2bf(val - bf2f(hb));
    }
}

// ---------------------------------------------------------------------------
extern "C" void kernel_launch(void* const* d_in, const int* in_sizes, int n_in,
                              void* d_out, int out_size, void* d_ws, size_t ws_size,
                              hipStream_t stream) {
    const float* x  = (const float*)d_in[0];
    const float* Wq = (const float*)d_in[1];
    const float* Wk = (const float*)d_in[2];
    const float* Wv = (const float*)d_in[3];
    const float* Wo = (const float*)d_in[4];
    float* out = (float*)d_out;

    char* base = (char*)d_ws;                       // 58 MB total
    const size_t MB = 1u << 20;
    float* kf = (float*)(base + 0);                 // 8 MB
    float* vf = (float*)(base + 8*MB);              // 8 MB
    unsigned short* xhi = (unsigned short*)(base + 16*MB);   // 4 MB
    unsigned short* xlo = (unsigned short*)(base + 20*MB);   // 4 MB
    unsigned short* wallhi = (unsigned short*)(base + 24*MB); // 6 MB [Wq|Wk|Wv]
    unsigned short* walllo = (unsigned short*)(base + 30*MB); // 6 MB
    unsigned short* wohi = (unsigned short*)(base + 36*MB);  // 2 MB
    unsigned short* wolo = (unsigned short*)(base + 38*MB);  // 2 MB
    unsigned short* qsphi = (unsigned short*)(base + 40*MB); // 4 MB [h][s][d]
    unsigned short* qsplo = (unsigned short*)(base + 44*MB);
    unsigned short* ksphi = (unsigned short*)(base + 48*MB); // 4 MB [h][s][d]
    unsigned short* ksplo = (unsigned short*)(base + 52*MB);
    // aliases (ordered reuse on the in-order stream):
    unsigned short* aohi = xhi;                     // x dead after gemm_qkv
    unsigned short* aolo = xlo;
    __half* part = (__half*)(base + 16*MB);         // 8 MB, x-region reuse:
                                                    // written by score_mfma (after
                                                    // gemm_qkv), read by reduce_infl,
                                                    // dead before attn_mfma writes ao
    const size_t CATB = (size_t)NH * NCATP * HD * 2; // 1.5 MB
    unsigned short* kchi = (unsigned short*)(base + 48*MB);  // after score_mfma
    unsigned short* kclo = (unsigned short*)(base + 48*MB + CATB);
    unsigned short* vthi = (unsigned short*)(base + 48*MB + 2*CATB);
    unsigned short* vtlo = (unsigned short*)(base + 48*MB + 3*CATB);
    // small buffers
    char* sm = base + 56*MB;
    float* ent  = (float*)sm;                 sm += NH*SEQ*4;
    float* mxa  = (float*)sm;                 sm += NH*SEQ*4;
    float* imp  = (float*)sm;                 sm += SEQ*4;
    int*   hh   = (int*)sm;                   sm += 256*4;
    float* wk   = (float*)sm;                 sm += NH*SEQ*4;
    float* wv   = (float*)sm;                 sm += NH*SEQ*4;
    float* red  = (float*)sm;                 // 64*SEQ*4 = 512 KB

    // 1. split inputs (one launch for all 4 weights)
    splitx_k<<<SEQ*HID/1024, 256, 0, stream>>>(x, xhi, xlo);
    splitw4_k<<<dim3(16,16,4), 256, 0, stream>>>(Wq, Wk, Wv, Wo,
                                                 wallhi, walllo, wohi, wolo);

    // 2. fused QKV projection (LDS-staged)
    gemm_lds<128, 64, 1><<<dim3(16, 48), 256, 0, stream>>>(
        xhi, xlo, wallhi, walllo, qsphi, qsplo, kf, ksphi, ksplo, vf, nullptr);

    // 3. score stats + heavy hitters (16-row blocks, grid 2048)
    score_mfma<<<dim3(NH, SEQ/16), 256, 0, stream>>>(qsphi, qsplo, ksphi, ksplo, ent, mxa, part);
    reduce_infl<<<dim3(SEQ/256, 64), 256, 0, stream>>>(part, red);
    importance_k<<<SEQ/256, 256, 0, stream>>>(ent, mxa, red, imp);
    topk_k<<<SEQ/256, 256, 0, stream>>>(imp, hh);

    // 4. compression weights + cat building (fused k/v variants)
    norms2_k<<<dim3(NH*SEQ/4, 2), 256, 0, stream>>>(kf, vf, wk, wv);
    softw2_k<<<dim3(NH, 2), 256, 0, stream>>>(wk, wv);
    pool2_k<<<dim3(NH*LCOMP*HD/256, 2), 256, 0, stream>>>(kf, vf, wk, wv,
                                                          kchi, kclo, vthi, vtlo);
    padzero_k<<<208, 256, 0, stream>>>(kchi, kclo, vthi, vtlo);
    gather_k<<<NH*NKH*HD/256, 256, 0, stream>>>(kf, vf, hh, kchi, kclo, vthi, vtlo);

    // 5. final attention (writes pre-split ao into x slot; part is dead)
    attn_mfma<<<dim3(NH, SEQ/16), 256, 0, stream>>>(qsphi, qsplo, kchi, kclo, vthi, vtlo, aohi, aolo);

    // 6. output projection (LDS-staged)
    gemm_lds<64, 64, 0><<<dim3(32, 16), 256, 0, stream>>>(
        aohi, aolo, wohi, wolo, nullptr, nullptr, nullptr, nullptr, nullptr, nullptr, out);
}

// Round 11
// 483.239 us; speedup vs baseline: 1.2240x; 1.2240x over previous
//
#include <hip/hip_runtime.h>
#include <hip/hip_fp16.h>
#include <math.h>

#define SEQ   2048
#define HID   1024
#define NH    16
#define HD    64
#define NKH   204          // heavy hitters = int(2048*0.1)
#define LCOMP 512          // compressed length = 2048/4
#define NCAT  716          // 204 + 512
#define NCATP 768          // padded to multiple of 64 (52 pad keys)
#define SCALE 0.125f       // 1/sqrt(64)

typedef __attribute__((ext_vector_type(8))) short short8;   // 8 bf16 (4 VGPRs)
typedef __attribute__((ext_vector_type(4))) float f32x4;    // MFMA accumulator

// ---- bf16 split helpers (RNE) -------------------------------------------
__device__ __forceinline__ short f2bf(float f) {
    unsigned u = __builtin_bit_cast(unsigned, f);
    u += 0x7FFFu + ((u >> 16) & 1u);
    return (short)(u >> 16);
}
__device__ __forceinline__ float bf2f(short h) {
    unsigned u = ((unsigned)(unsigned short)h) << 16;
    return __builtin_bit_cast(float, u);
}

// ---------------------------------------------------------------------------
// One-pass splitters: f32 -> bf16 hi/lo.
// ---------------------------------------------------------------------------
__global__ __launch_bounds__(256) void splitx_k(const float* __restrict__ X,
                                                unsigned short* __restrict__ hi,
                                                unsigned short* __restrict__ lo) {
    size_t g = ((size_t)blockIdx.x * 256 + threadIdx.x) * 4;
    float4 v4 = *(const float4*)(X + g);
    ushort4 h4, l4;
    short hb;
    hb = f2bf(v4.x); h4.x = hb; l4.x = (unsigned short)f2bf(v4.x - bf2f(hb));
    hb = f2bf(v4.y); h4.y = hb; l4.y = (unsigned short)f2bf(v4.y - bf2f(hb));
    hb = f2bf(v4.z); h4.z = hb; l4.z = (unsigned short)f2bf(v4.z - bf2f(hb));
    hb = f2bf(v4.w); h4.w = hb; l4.w = (unsigned short)f2bf(v4.w - bf2f(hb));
    *(ushort4*)(hi + g) = h4;
    *(ushort4*)(lo + g) = l4;
}

// All 4 weight splits in one launch; blockIdx.z picks src/dst (wave-uniform).
__global__ __launch_bounds__(256) void splitw4_k(const float* __restrict__ W0,
                                                 const float* __restrict__ W1,
                                                 const float* __restrict__ W2,
                                                 const float* __restrict__ W3,
                                                 unsigned short* __restrict__ h012,
                                                 unsigned short* __restrict__ l012,
                                                 unsigned short* __restrict__ h3,
                                                 unsigned short* __restrict__ l3) {
    __shared__ float tile[64][65];
    int z = blockIdx.z;
    const float* W = (z == 0) ? W0 : (z == 1) ? W1 : (z == 2) ? W2 : W3;
    unsigned short* hi = (z == 3) ? h3 : h012 + (size_t)z * HID * HID;
    unsigned short* lo = (z == 3) ? l3 : l012 + (size_t)z * HID * HID;
    int n0 = blockIdx.x * 64, k0 = blockIdx.y * 64;
    int t = threadIdx.x;
    int r = t >> 4, c4 = (t & 15) * 4;
    #pragma unroll
    for (int i = 0; i < 4; ++i) {
        float4 v4 = *(const float4*)(W + (size_t)(k0 + i*16 + r) * HID + n0 + c4);
        tile[i*16 + r][c4+0] = v4.x; tile[i*16 + r][c4+1] = v4.y;
        tile[i*16 + r][c4+2] = v4.z; tile[i*16 + r][c4+3] = v4.w;
    }
    __syncthreads();
    #pragma unroll
    for (int i = 0; i < 4; ++i) {
        int n = i*16 + r;
        float v0 = tile[c4+0][n], v1 = tile[c4+1][n];
        float v2 = tile[c4+2][n], v3 = tile[c4+3][n];
        ushort4 h4, l4;
        short hb;
        hb = f2bf(v0); h4.x = hb; l4.x = (unsigned short)f2bf(v0 - bf2f(hb));
        hb = f2bf(v1); h4.y = hb; l4.y = (unsigned short)f2bf(v1 - bf2f(hb));
        hb = f2bf(v2); h4.z = hb; l4.z = (unsigned short)f2bf(v2 - bf2f(hb));
        hb = f2bf(v3); h4.w = hb; l4.w = (unsigned short)f2bf(v3 - bf2f(hb));
        size_t o = (size_t)(n0 + n) * HID + k0 + c4;
        *(ushort4*)(hi + o) = h4;
        *(ushort4*)(lo + o) = l4;
    }
}

// ---------------------------------------------------------------------------
// LDS-staged bf16x3 MFMA GEMM.  Block = BM x BN, BK=32, 4 waves,
// wave = (BM/2)m x (BN/2)n.  MODE 1 = fused QKV epilogue, MODE 0 = f32 C.
// ---------------------------------------------------------------------------
template<int BM, int BN, int MODE>
__global__ __launch_bounds__(256) void gemm_lds(const unsigned short* __restrict__ Ahi,
                                                const unsigned short* __restrict__ Alo,
                                                const unsigned short* __restrict__ Bthi,
                                                const unsigned short* __restrict__ Btlo,
                                                unsigned short* __restrict__ qhi,
                                                unsigned short* __restrict__ qlo,
                                                float* __restrict__ kf,
                                                unsigned short* __restrict__ khi,
                                                unsigned short* __restrict__ klo,
                                                float* __restrict__ vf,
                                                float* __restrict__ Cf) {
    constexpr int WM = BM / 2, WN = BN / 2;
    constexpr int MT = WM / 16, NT = WN / 16;
    __shared__ __align__(16) unsigned short Ah_s[BM * 32];
    __shared__ __align__(16) unsigned short Al_s[BM * 32];
    __shared__ __align__(16) unsigned short Bh_s[BN * 32];
    __shared__ __align__(16) unsigned short Bl_s[BN * 32];
    int t = threadIdx.x, lane = t & 63, w = t >> 6;
    int quad = lane >> 4, c16 = lane & 15;
    int m0 = blockIdx.x * BM, n0 = blockIdx.y * BN;
    int moff = (w & 1) * WM, noff = (w >> 1) * WN;
    int sr = t >> 2, skq = (t & 3) * 8;          // staging: row, k-offset

    f32x4 acc[MT][NT];
    #pragma unroll
    for (int mt = 0; mt < MT; ++mt)
        #pragma unroll
        for (int nt = 0; nt < NT; ++nt)
            acc[mt][nt] = (f32x4){0.f, 0.f, 0.f, 0.f};

    for (int kt = 0; kt < HID; kt += 32) {
        __syncthreads();
        #pragma unroll
        for (int p = 0; p < BM / 64; ++p) {
            int row = p * 64 + sr;
            *(short8*)&Ah_s[row * 32 + skq] =
                *(const short8*)(Ahi + (size_t)(m0 + row) * HID + kt + skq);
            *(short8*)&Al_s[row * 32 + skq] =
                *(const short8*)(Alo + (size_t)(m0 + row) * HID + kt + skq);
        }
        #pragma unroll
        for (int p = 0; p < BN / 64; ++p) {
            int row = p * 64 + sr;
            *(short8*)&Bh_s[row * 32 + skq] =
                *(const short8*)(Bthi + (size_t)(n0 + row) * HID + kt + skq);
            *(short8*)&Bl_s[row * 32 + skq] =
                *(const short8*)(Btlo + (size_t)(n0 + row) * HID + kt + skq);
        }
        __syncthreads();
        short8 Bh[NT], Bl[NT];
        #pragma unroll
        for (int nt = 0; nt < NT; ++nt) {
            int row = noff + nt * 16 + c16;
            Bh[nt] = *(const short8*)&Bh_s[row * 32 + quad * 8];
            Bl[nt] = *(const short8*)&Bl_s[row * 32 + quad * 8];
        }
        #pragma unroll
        for (int mt = 0; mt < MT; ++mt) {
            int row = moff + mt * 16 + c16;
            short8 Ah = *(const short8*)&Ah_s[row * 32 + quad * 8];
            short8 Al = *(const short8*)&Al_s[row * 32 + quad * 8];
            #pragma unroll
            for (int nt = 0; nt < NT; ++nt) {
                acc[mt][nt] = __builtin_amdgcn_mfma_f32_16x16x32_bf16(Ah, Bh[nt], acc[mt][nt], 0, 0, 0);
                acc[mt][nt] = __builtin_amdgcn_mfma_f32_16x16x32_bf16(Al, Bh[nt], acc[mt][nt], 0, 0, 0);
                acc[mt][nt] = __builtin_amdgcn_mfma_f32_16x16x32_bf16(Ah, Bl[nt], acc[mt][nt], 0, 0, 0);
            }
        }
    }

    #pragma unroll
    for (int mt = 0; mt < MT; ++mt)
    #pragma unroll
    for (int nt = 0; nt < NT; ++nt)
    #pragma unroll
    for (int i = 0; i < 4; ++i) {
        int m  = m0 + moff + mt * 16 + quad * 4 + i;
        int ng = n0 + noff + nt * 16 + c16;
        float val = acc[mt][nt][i];
        if (MODE == 1) {
            int seg = ng >> 10;            // 0=q, 1=k, 2=v
            int nl  = ng & 1023;
            if (seg == 0) {
                size_t o = ((size_t)(nl >> 6) * SEQ + m) * HD + (nl & 63);
                short hb = f2bf(val);
                qhi[o] = (unsigned short)hb;
                qlo[o] = (unsigned short)f2bf(val - bf2f(hb));
            } else if (seg == 1) {
                kf[(size_t)m * HID + nl] = val;
                size_t o = ((size_t)(nl >> 6) * SEQ + m) * HD + (nl & 63);
                short hb = f2bf(val);
                khi[o] = (unsigned short)hb;
                klo[o] = (unsigned short)f2bf(val - bf2f(hb));
            } else {
                vf[(size_t)m * HID + nl] = val;
            }
        } else {
            Cf[(size_t)m * HID + ng] = val;
        }
    }
}

// ---------------------------------------------------------------------------
// Score stats (round-9 structure — measured best at 134 us): 32-row blocks,
// two-pass recompute, no score storage.  Wave w owns keys [w*512,+512).
// ONE delta vs r9: grid transposed to (qb, head) so the 64 consecutive
// blocks in dispatch order share one head -> K slice stays hot in XCD L2.
// ---------------------------------------------------------------------------
__global__ __launch_bounds__(256) void score_mfma(const unsigned short* __restrict__ qhi,
                                                  const unsigned short* __restrict__ qlo,
                                                  const unsigned short* __restrict__ khi,
                                                  const unsigned short* __restrict__ klo,
                                                  float* __restrict__ ent,
                                                  float* __restrict__ mxa,
                                                  __half* __restrict__ part) {
    __shared__ float redm[4][32], redl[4][32], rede[4][32];
    int h  = blockIdx.y;                 // head-major locality (swizzle)
    int qb = blockIdx.x;
    int m0 = qb * 32;
    int t  = threadIdx.x;
    int lane = t & 63, w = t >> 6;
    int quad = lane >> 4, c16 = lane & 15;

    short8 Ah0[2], Ah1[2], Al0[2], Al1[2];
    #pragma unroll
    for (int rt = 0; rt < 2; ++rt) {
        const unsigned short* qph = qhi + ((size_t)h * SEQ + m0 + rt*16 + c16) * HD;
        const unsigned short* qpl = qlo + ((size_t)h * SEQ + m0 + rt*16 + c16) * HD;
        Ah0[rt] = *(const short8*)(qph + quad*8);
        Ah1[rt] = *(const short8*)(qph + 32 + quad*8);
        Al0[rt] = *(const short8*)(qpl + quad*8);
        Al1[rt] = *(const short8*)(qpl + 32 + quad*8);
    }

    float l[2][4] = {}, ee[2][4] = {};
    float mx[2][4] = {{-1e30f,-1e30f,-1e30f,-1e30f},{-1e30f,-1e30f,-1e30f,-1e30f}};
    #pragma unroll
    for (int nt = 0; nt < 32; ++nt) {
        int key = (w * 32 + nt) * 16 + c16;
        const unsigned short* kbh = khi + ((size_t)h * SEQ + key) * HD;
        const unsigned short* kbl = klo + ((size_t)h * SEQ + key) * HD;
        short8 Bh0 = *(const short8*)(kbh + quad*8);
        short8 Bh1 = *(const short8*)(kbh + 32 + quad*8);
        short8 Bl0 = *(const short8*)(kbl + quad*8);
        short8 Bl1 = *(const short8*)(kbl + 32 + quad*8);
        #pragma unroll
        for (int rt = 0; rt < 2; ++rt) {
            f32x4 acc = {0.f, 0.f, 0.f, 0.f};
            acc = __builtin_amdgcn_mfma_f32_16x16x32_bf16(Ah0[rt], Bh0, acc, 0, 0, 0);
            acc = __builtin_amdgcn_mfma_f32_16x16x32_bf16(Al0[rt], Bh0, acc, 0, 0, 0);
            acc = __builtin_amdgcn_mfma_f32_16x16x32_bf16(Ah0[rt], Bl0, acc, 0, 0, 0);
            acc = __builtin_amdgcn_mfma_f32_16x16x32_bf16(Ah1[rt], Bh1, acc, 0, 0, 0);
            acc = __builtin_amdgcn_mfma_f32_16x16x32_bf16(Al1[rt], Bh1, acc, 0, 0, 0);
            acc = __builtin_amdgcn_mfma_f32_16x16x32_bf16(Ah1[rt], Bl1, acc, 0, 0, 0);
            #pragma unroll
            for (int i = 0; i < 4; ++i) {
                float s = acc[i] * SCALE;
                float tt = __expf(s);          // safe: |s| << 88
                l[rt][i] += tt;
                ee[rt][i] += tt * s;
                mx[rt][i] = fmaxf(mx[rt][i], s);
            }
        }
    }
    #pragma unroll
    for (int rt = 0; rt < 2; ++rt)
    #pragma unroll
    for (int i = 0; i < 4; ++i) {
        #pragma unroll
        for (int off = 1; off <= 8; off <<= 1) {
            l[rt][i]  += __shfl_xor(l[rt][i], off);
            ee[rt][i] += __shfl_xor(ee[rt][i], off);
            mx[rt][i]  = fmaxf(mx[rt][i], __shfl_xor(mx[rt][i], off));
        }
    }
    if (c16 == 0) {
        #pragma unroll
        for (int rt = 0; rt < 2; ++rt)
        #pragma unroll
        for (int i = 0; i < 4; ++i) {
            int row = rt*16 + quad*4 + i;
            redl[w][row] = l[rt][i];
            rede[w][row] = ee[rt][i];
            redm[w][row] = mx[rt][i];
        }
    }
    __syncthreads();
    float inv[2][4];
    #pragma unroll
    for (int rt = 0; rt < 2; ++rt)
    #pragma unroll
    for (int i = 0; i < 4; ++i) {
        int row = rt*16 + quad*4 + i;
        float lf = redl[0][row] + redl[1][row] + redl[2][row] + redl[3][row];
        inv[rt][i] = 1.f / lf;
        if (w == 0 && c16 == 0) {
            float eef = rede[0][row] + rede[1][row] + rede[2][row] + rede[3][row];
            float mf  = fmaxf(fmaxf(redm[0][row], redm[1][row]),
                              fmaxf(redm[2][row], redm[3][row]));
            mxa[h*SEQ + m0 + row] = __expf(mf) * inv[rt][i];
            ent[h*SEQ + m0 + row] = __logf(lf) - eef * inv[rt][i];
        }
    }

    // ---- pass 2: recompute QK, emit influence column sums (f16) ----
    __half* pslab = part + (size_t)(h * (SEQ/32) + qb) * SEQ;
    #pragma unroll
    for (int nt = 0; nt < 32; ++nt) {
        int key = (w * 32 + nt) * 16 + c16;
        const unsigned short* kbh = khi + ((size_t)h * SEQ + key) * HD;
        const unsigned short* kbl = klo + ((size_t)h * SEQ + key) * HD;
        short8 Bh0 = *(const short8*)(kbh + quad*8);
        short8 Bh1 = *(const short8*)(kbh + 32 + quad*8);
        short8 Bl0 = *(const short8*)(kbl + quad*8);
        short8 Bl1 = *(const short8*)(kbl + 32 + quad*8);
        float cs = 0.f;
        #pragma unroll
        for (int rt = 0; rt < 2; ++rt) {
            f32x4 acc = {0.f, 0.f, 0.f, 0.f};
            acc = __builtin_amdgcn_mfma_f32_16x16x32_bf16(Ah0[rt], Bh0, acc, 0, 0, 0);
            acc = __builtin_amdgcn_mfma_f32_16x16x32_bf16(Al0[rt], Bh0, acc, 0, 0, 0);
            acc = __builtin_amdgcn_mfma_f32_16x16x32_bf16(Ah0[rt], Bl0, acc, 0, 0, 0);
            acc = __builtin_amdgcn_mfma_f32_16x16x32_bf16(Ah1[rt], Bh1, acc, 0, 0, 0);
            acc = __builtin_amdgcn_mfma_f32_16x16x32_bf16(Al1[rt], Bh1, acc, 0, 0, 0);
            acc = __builtin_amdgcn_mfma_f32_16x16x32_bf16(Ah1[rt], Bl1, acc, 0, 0, 0);
            #pragma unroll
            for (int i = 0; i < 4; ++i)
                cs += __expf(acc[i] * SCALE) * inv[rt][i];
        }
        cs += __shfl_xor(cs, 16);
        cs += __shfl_xor(cs, 32);           // sum over all 32 rows (4 quads)
        if (lane < 16) pslab[(w*32 + nt)*16 + lane] = __float2half(cs);
    }
}

// stage-1 influence reduction: red[g][s] = sum of 16 slabs (f16 -> f32)
__global__ __launch_bounds__(256) void reduce_infl(const __half* __restrict__ part,
                                                   float* __restrict__ red) {
    int s = blockIdx.x * 256 + threadIdx.x;
    int g = blockIdx.y;
    const __half* p = part + (size_t)g * 16 * SEQ + s;
    float a = 0.f;
    #pragma unroll
    for (int i = 0; i < 16; ++i) a += __half2float(p[(size_t)i * SEQ]);
    red[(size_t)g * SEQ + s] = a;
}

__global__ __launch_bounds__(256) void importance_k(const float* __restrict__ ent,
                                                    const float* __restrict__ mxa,
                                                    const float* __restrict__ red,
                                                    float* __restrict__ imp) {
    int s = blockIdx.x * 256 + threadIdx.x;
    float es = 0.f, ms = 0.f;
    #pragma unroll
    for (int h = 0; h < NH; ++h) { es += ent[h*SEQ + s]; ms += mxa[h*SEQ + s]; }
    float inf = 0.f;
    #pragma unroll 8
    for (int g = 0; g < 64; ++g) inf += red[(size_t)g * SEQ + s];
    imp[s] = (-0.4f*es + 0.3f*ms + 0.3f*inf) * (1.f/16.f);
}

// Deterministic top-k by rank counting (matches lax.top_k set semantics).
__global__ __launch_bounds__(256) void topk_k(const float* __restrict__ imp,
                                              int* __restrict__ hh) {
    __shared__ float si[SEQ];
    int t = threadIdx.x, s = blockIdx.x * 256 + t;
    for (int i = t; i < SEQ; i += 256) si[i] = imp[i];
    __syncthreads();
    float v = si[s];
    int rank = 0;
    #pragma unroll 1
    for (int i = 0; i < SEQ; ++i) {
        float u = si[i];
        rank += (u > v) || (u == v && i < s);
    }
    if (rank < NKH) hh[rank] = s;
}

// per-(h,s) L2 norms for BOTH k and v (blockIdx.y selects tensor)
__global__ __launch_bounds__(256) void norms2_k(const float* __restrict__ kf,
                                                const float* __restrict__ vf,
                                                float* __restrict__ wk,
                                                float* __restrict__ wv) {
    int sel = blockIdx.y;
    const float* x = sel ? vf : kf;
    float* n = sel ? wv : wk;
    int t = threadIdx.x;
    int wid = blockIdx.x * 4 + (t >> 6);
    int lane = t & 63;
    int h = wid >> 11, s = wid & 2047;
    float v = x[(size_t)s * HID + h * HD + lane];
    float ss = v * v;
    #pragma unroll
    for (int off = 32; off; off >>= 1) ss += __shfl_xor(ss, off);
    if (lane == 0) n[h*SEQ + s] = sqrtf(ss);
}

// in-place softmax over SEQ per head for BOTH wk and wv
__global__ __launch_bounds__(256) void softw2_k(float* __restrict__ wk,
                                                float* __restrict__ wv) {
    __shared__ float red[8];
    int h = blockIdx.x, t = threadIdx.x, lane = t & 63, w = t >> 6;
    float* nh = (blockIdx.y ? wv : wk) + (size_t)h * SEQ;
    float m = -1e30f;
    for (int i = t; i < SEQ; i += 256) m = fmaxf(m, nh[i]);
    #pragma unroll
    for (int off = 32; off; off >>= 1) m = fmaxf(m, __shfl_xor(m, off));
    if (lane == 0) red[w] = m;
    __syncthreads();
    m = fmaxf(fmaxf(red[0], red[1]), fmaxf(red[2], red[3]));
    float z = 0.f;
    for (int i = t; i < SEQ; i += 256) z += __expf(nh[i] - m);
    #pragma unroll
    for (int off = 32; off; off >>= 1) z += __shfl_xor(z, off);
    if (lane == 0) red[4 + w] = z;
    __syncthreads();
    z = red[4] + red[5] + red[6] + red[7];
    for (int i = t; i < SEQ; i += 256) nh[i] = __expf(nh[i] - m) / z;
}

// group-4 weighted pooling of K (direct) and V (transposed) in one launch
__global__ __launch_bounds__(256) void pool2_k(const float* __restrict__ kf,
                                               const float* __restrict__ vf,
                                               const float* __restrict__ wk,
                                               const float* __restrict__ wv,
                                               unsigned short* __restrict__ khi,
                                               unsigned short* __restrict__ klo,
                                               unsigned short* __restrict__ vthi,
                                               unsigned short* __restrict__ vtlo) {
    int sel = blockIdx.y;
    const float* src = sel ? vf : kf;
    const float* w   = sel ? wv : wk;
    int g = blockIdx.x * 256 + threadIdx.x;
    int d = g & 63, rest = g >> 6;
    int l = rest & 511, h = rest >> 9;
    const float* wp = w + (size_t)h * SEQ + l * 4;
    float w0 = wp[0], w1 = wp[1], w2 = wp[2], w3 = wp[3];
    float wsum = w0 + w1 + w2 + w3 + 1e-8f;
    size_t base = (size_t)(l*4) * HID + h * HD + d;
    float val = (src[base]*w0 + src[base+HID]*w1 + src[base+2*HID]*w2 + src[base+3*HID]*w3) / wsum;
    short hb = f2bf(val);
    if (sel) {
        size_t dst = ((size_t)h * HD + d) * NCATP + NKH + l;
        vthi[dst] = (unsigned short)hb;
        vtlo[dst] = (unsigned short)f2bf(val - bf2f(hb));
    } else {
        size_t dst = ((size_t)h * NCATP + NKH + l) * HD + d;
        khi[dst] = (unsigned short)hb;
        klo[dst] = (unsigned short)f2bf(val - bf2f(hb));
    }
}

// gather heavy-hitter k/v rows -> pre-split bf16 (K direct, V transposed)
__global__ __launch_bounds__(256) void gather_k(const float* __restrict__ k,
                                                const float* __restrict__ v,
                                                const int* __restrict__ hh,
                                                unsigned short* __restrict__ khi,
                                                unsigned short* __restrict__ klo,
                                                unsigned short* __restrict__ vthi,
                                                unsigned short* __restrict__ vtlo) {
    int g = blockIdx.x * 256 + threadIdx.x;
    int d = g & 63, rest = g >> 6;
    int i = rest % NKH, h = rest / NKH;
    int s = hh[i];
    float kv = k[(size_t)s * HID + h * HD + d];
    float vv = v[(size_t)s * HID + h * HD + d];
    size_t kd = ((size_t)h * NCATP + i) * HD + d;
    size_t vd = ((size_t)h * HD + d) * NCATP + i;
    short hb = f2bf(kv);
    khi[kd] = (unsigned short)hb;
    klo[kd] = (unsigned short)f2bf(kv - bf2f(hb));
    hb = f2bf(vv);
    vthi[vd] = (unsigned short)hb;
    vtlo[vd] = (unsigned short)f2bf(vv - bf2f(hb));
}

// zero the 52 pad keys per head in all four split arrays
__global__ __launch_bounds__(256) void padzero_k(unsigned short* __restrict__ khi,
                                                 unsigned short* __restrict__ klo,
                                                 unsigned short* __restrict__ vthi,
                                                 unsigned short* __restrict__ vtlo) {
    int g = blockIdx.x * 256 + threadIdx.x;
    if (g >= NH * (NCATP - NCAT) * HD) return;
    int d = g & 63, rest = g >> 6;
    int i = rest % (NCATP - NCAT), h = rest / (NCATP - NCAT);
    size_t kd = ((size_t)h * NCATP + NCAT + i) * HD + d;
    size_t vd = ((size_t)h * HD + d) * NCATP + NCAT + i;
    khi[kd] = 0; klo[kd] = 0;
    vthi[vd] = 0; vtlo[vd] = 0;
}

// ---------------------------------------------------------------------------
// Final attention via bf16x3 MFMA + __expf (unchanged).
// ---------------------------------------------------------------------------
__global__ __launch_bounds__(256) void attn_mfma(const unsigned short* __restrict__ qhi,
                                                 const unsigned short* __restrict__ qlo,
                                                 const unsigned short* __restrict__ kchi,
                                                 const unsigned short* __restrict__ kclo,
                                                 const unsigned short* __restrict__ vthi,
                                                 const unsigned short* __restrict__ vtlo,
                                                 unsigned short* __restrict__ aohi,
                                                 unsigned short* __restrict__ aolo) {
    __shared__ unsigned short phi[16][776];
    __shared__ unsigned short plo[16][776];
    __shared__ float redm[4][16], redl[4][16];
    int h  = blockIdx.x;
    int m0 = blockIdx.y * 16;
    int t  = threadIdx.x;
    int lane = t & 63, w = t >> 6;
    int quad = lane >> 4, c16 = lane & 15;

    const unsigned short* qph = qhi + ((size_t)h * SEQ + m0 + c16) * HD;
    const unsigned short* qpl = qlo + ((size_t)h * SEQ + m0 + c16) * HD;
    short8 Ah0 = *(const short8*)(qph + quad*8);
    short8 Ah1 = *(const short8*)(qph + 32 + quad*8);
    short8 Al0 = *(const short8*)(qpl + quad*8);
    short8 Al1 = *(const short8*)(qpl + 32 + quad*8);

    float sreg[12][4];
    #pragma unroll
    for (int nt = 0; nt < 12; ++nt) {
        int key = w*192 + nt*16 + c16;
        const unsigned short* kbh = kchi + ((size_t)h * NCATP + key) * HD;
        const unsigned short* kbl = kclo + ((size_t)h * NCATP + key) * HD;
        short8 Bh0 = *(const short8*)(kbh + quad*8);
        short8 Bh1 = *(const short8*)(kbh + 32 + quad*8);
        short8 Bl0 = *(const short8*)(kbl + quad*8);
        short8 Bl1 = *(const short8*)(kbl + 32 + quad*8);
        f32x4 acc = {0.f, 0.f, 0.f, 0.f};
        acc = __builtin_amdgcn_mfma_f32_16x16x32_bf16(Ah0, Bh0, acc, 0, 0, 0);
        acc = __builtin_amdgcn_mfma_f32_16x16x32_bf16(Al0, Bh0, acc, 0, 0, 0);
        acc = __builtin_amdgcn_mfma_f32_16x16x32_bf16(Ah0, Bl0, acc, 0, 0, 0);
        acc = __builtin_amdgcn_mfma_f32_16x16x32_bf16(Ah1, Bh1, acc, 0, 0, 0);
        acc = __builtin_amdgcn_mfma_f32_16x16x32_bf16(Al1, Bh1, acc, 0, 0, 0);
        acc = __builtin_amdgcn_mfma_f32_16x16x32_bf16(Ah1, Bl1, acc, 0, 0, 0);
        bool bad = key >= NCAT;
        #pragma unroll
        for (int i = 0; i < 4; ++i)
            sreg[nt][i] = bad ? -1e30f : acc[i] * SCALE;
    }

    float m[4], l[4];
    #pragma unroll
    for (int i = 0; i < 4; ++i) {
        float mm = -1e30f;
        #pragma unroll
        for (int nt = 0; nt < 12; ++nt) mm = fmaxf(mm, sreg[nt][i]);
        #pragma unroll
        for (int off = 1; off <= 8; off <<= 1) mm = fmaxf(mm, __shfl_xor(mm, off));
        m[i] = mm;
    }
    if (c16 == 0) {
        #pragma unroll
        for (int i = 0; i < 4; ++i) redm[w][quad*4 + i] = m[i];
    }
    __syncthreads();
    #pragma unroll
    for (int i = 0; i < 4; ++i) {
        int row = quad*4 + i;
        m[i] = fmaxf(fmaxf(redm[0][row], redm[1][row]),
                     fmaxf(redm[2][row], redm[3][row]));
    }
    #pragma unroll
    for (int i = 0; i < 4; ++i) {
        float ll = 0.f;
        #pragma unroll
        for (int nt = 0; nt < 12; ++nt) ll += __expf(sreg[nt][i] - m[i]);
        #pragma unroll
        for (int off = 1; off <= 8; off <<= 1) ll += __shfl_xor(ll, off);
        l[i] = ll;
    }
    if (c16 == 0) {
        #pragma unroll
        for (int i = 0; i < 4; ++i) redl[w][quad*4 + i] = l[i];
    }
    __syncthreads();
    float inv[4];
    #pragma unroll
    for (int i = 0; i < 4; ++i) {
        int row = quad*4 + i;
        inv[i] = 1.f / (redl[0][row] + redl[1][row] + redl[2][row] + redl[3][row]);
    }

    #pragma unroll
    for (int nt = 0; nt < 12; ++nt) {
        int key = w*192 + nt*16 + c16;
        #pragma unroll
        for (int i = 0; i < 4; ++i) {
            float p = __expf(sreg[nt][i] - m[i]) * inv[i];
            short ph = f2bf(p);
            phi[quad*4 + i][key] = (unsigned short)ph;
            plo[quad*4 + i][key] = (unsigned short)f2bf(p - bf2f(ph));
        }
    }
    __syncthreads();

    int dim = w*16 + c16;
    const unsigned short* vh = vthi + ((size_t)h * HD + dim) * NCATP;
    const unsigned short* vl = vtlo + ((size_t)h * HD + dim) * NCATP;
    f32x4 ohh = {0.f,0.f,0.f,0.f}, olh = {0.f,0.f,0.f,0.f}, ohl = {0.f,0.f,0.f,0.f};
    #pragma unroll 4
    for (int s = 0; s < 24; ++s) {
        int k0 = s*32 + quad*8;
        short8 Ph = *(const short8*)&phi[c16][k0];
        short8 Pl = *(const short8*)&plo[c16][k0];
        short8 Vh = *(const short8*)(vh + k0);
        short8 Vl = *(const short8*)(vl + k0);
        ohh = __builtin_amdgcn_mfma_f32_16x16x32_bf16(Ph, Vh, ohh, 0, 0, 0);
        olh = __builtin_amdgcn_mfma_f32_16x16x32_bf16(Pl, Vh, olh, 0, 0, 0);
        ohl = __builtin_amdgcn_mfma_f32_16x16x32_bf16(Ph, Vl, ohl, 0, 0, 0);
    }
    #pragma unroll
    for (int i = 0; i < 4; ++i) {
        float val = ohh[i] + olh[i] + ohl[i];
        size_t o = (size_t)(m0 + quad*4 + i) * HID + h * HD + dim;
        short hb = f2bf(val);
        aohi[o] = (unsigned short)hb;
        aolo[o] = (unsigned short)f2bf(val - bf2f(hb));
    }
}

// ---------------------------------------------------------------------------
extern "C" void kernel_launch(void* const* d_in, const int* in_sizes, int n_in,
                              void* d_out, int out_size, void* d_ws, size_t ws_size,
                              hipStream_t stream) {
    const float* x  = (const float*)d_in[0];
    const float* Wq = (const float*)d_in[1];
    const float* Wk = (const float*)d_in[2];
    const float* Wv = (const float*)d_in[3];
    const float* Wo = (const float*)d_in[4];
    float* out = (float*)d_out;

    char* base = (char*)d_ws;                       // 58 MB total
    const size_t MB = 1u << 20;
    float* kf = (float*)(base + 0);                 // 8 MB
    float* vf = (float*)(base + 8*MB);              // 8 MB
    unsigned short* xhi = (unsigned short*)(base + 16*MB);   // 4 MB
    unsigned short* xlo = (unsigned short*)(base + 20*MB);   // 4 MB
    unsigned short* wallhi = (unsigned short*)(base + 24*MB); // 6 MB [Wq|Wk|Wv]
    unsigned short* walllo = (unsigned short*)(base + 30*MB); // 6 MB
    unsigned short* wohi = (unsigned short*)(base + 36*MB);  // 2 MB
    unsigned short* wolo = (unsigned short*)(base + 38*MB);  // 2 MB
    unsigned short* qsphi = (unsigned short*)(base + 40*MB); // 4 MB [h][s][d]
    unsigned short* qsplo = (unsigned short*)(base + 44*MB);
    unsigned short* ksphi = (unsigned short*)(base + 48*MB); // 4 MB [h][s][d]
    unsigned short* ksplo = (unsigned short*)(base + 52*MB);
    // aliases (ordered reuse on the in-order stream):
    unsigned short* aohi = xhi;                     // x dead after gemm_qkv
    unsigned short* aolo = xlo;
    __half* part = (__half*)(base + 16*MB);         // 4 MB, x-region reuse:
                                                    // written after gemm_qkv,
                                                    // dead before attn_mfma writes ao
    const size_t CATB = (size_t)NH * NCATP * HD * 2; // 1.5 MB
    unsigned short* kchi = (unsigned short*)(base + 48*MB);  // after score_mfma
    unsigned short* kclo = (unsigned short*)(base + 48*MB + CATB);
    unsigned short* vthi = (unsigned short*)(base + 48*MB + 2*CATB);
    unsigned short* vtlo = (unsigned short*)(base + 48*MB + 3*CATB);
    // small buffers
    char* sm = base + 56*MB;
    float* ent  = (float*)sm;                 sm += NH*SEQ*4;
    float* mxa  = (float*)sm;                 sm += NH*SEQ*4;
    float* imp  = (float*)sm;                 sm += SEQ*4;
    int*   hh   = (int*)sm;                   sm += 256*4;
    float* wk   = (float*)sm;                 sm += NH*SEQ*4;
    float* wv   = (float*)sm;                 sm += NH*SEQ*4;
    float* red  = (float*)sm;                 // 64*SEQ*4 = 512 KB

    // 1. split inputs (one launch for all 4 weights)
    splitx_k<<<SEQ*HID/1024, 256, 0, stream>>>(x, xhi, xlo);
    splitw4_k<<<dim3(16,16,4), 256, 0, stream>>>(Wq, Wk, Wv, Wo,
                                                 wallhi, walllo, wohi, wolo);

    // 2. fused QKV projection (LDS-staged)
    gemm_lds<128, 64, 1><<<dim3(16, 48), 256, 0, stream>>>(
        xhi, xlo, wallhi, walllo, qsphi, qsplo, kf, ksphi, ksplo, vf, nullptr);

    // 3. score stats + heavy hitters (32-row blocks, head-major grid)
    score_mfma<<<dim3(SEQ/32, NH), 256, 0, stream>>>(qsphi, qsplo, ksphi, ksplo, ent, mxa, part);
    reduce_infl<<<dim3(SEQ/256, 64), 256, 0, stream>>>(part, red);
    importance_k<<<SEQ/256, 256, 0, stream>>>(ent, mxa, red, imp);
    topk_k<<<SEQ/256, 256, 0, stream>>>(imp, hh);

    // 4. compression weights + cat building (fused k/v variants)
    norms2_k<<<dim3(NH*SEQ/4, 2), 256, 0, stream>>>(kf, vf, wk, wv);
    softw2_k<<<dim3(NH, 2), 256, 0, stream>>>(wk, wv);
    pool2_k<<<dim3(NH*LCOMP*HD/256, 2), 256, 0, stream>>>(kf, vf, wk, wv,
                                                          kchi, kclo, vthi, vtlo);
    padzero_k<<<208, 256, 0, stream>>>(kchi, kclo, vthi, vtlo);
    gather_k<<<NH*NKH*HD/256, 256, 0, stream>>>(kf, vf, hh, kchi, kclo, vthi, vtlo);

    // 5. final attention (writes pre-split ao into x slot; part is dead)
    attn_mfma<<<dim3(NH, SEQ/16), 256, 0, stream>>>(qsphi, qsplo, kchi, kclo, vthi, vtlo, aohi, aolo);

    // 6. output projection (LDS-staged)
    gemm_lds<64, 64, 0><<<dim3(32, 16), 256, 0, stream>>>(
        aohi, aolo, wohi, wolo, nullptr, nullptr, nullptr, nullptr, nullptr, nullptr, out);
}